// Round 2
// baseline (189.191 us; speedup 1.0000x reference)
//
#include <hip/hip_runtime.h>
#include <hip/hip_bf16.h>

typedef __attribute__((ext_vector_type(8))) short short8;
typedef __attribute__((ext_vector_type(4))) float f32x4;

#define B_ROWS 8192
#define DIM 256
#define CS 4
#define MARGIN_F 0.2f

__device__ __forceinline__ unsigned short f2bf(float x) {
  unsigned int u = __float_as_uint(x);
  unsigned int r = (u + 0x7fffu + ((u >> 16) & 1u)) >> 16;
  return (unsigned short)r;
}
__device__ __forceinline__ float bf2f(unsigned short h) {
  return __uint_as_float(((unsigned int)h) << 16);
}

__device__ __forceinline__ void gload_lds16(const void* g, void* l) {
  __builtin_amdgcn_global_load_lds(
      (const __attribute__((address_space(1))) unsigned int*)g,
      (__attribute__((address_space(3))) unsigned int*)l, 16, 0, 0);
}

// ---- 1. normalize rows (fp32), write bf16 e, scatter-add proto sums ----
__global__ __launch_bounds__(256) void k_norm_scatter(
    const float* __restrict__ emb, const int* __restrict__ labels,
    unsigned short* __restrict__ ebf, float* __restrict__ sums,
    int* __restrict__ counts) {
  int wid = threadIdx.x >> 6, lane = threadIdx.x & 63;
  int row = blockIdx.x * 4 + wid;
  const float4 v = *reinterpret_cast<const float4*>(emb + row * DIM + lane * 4);
  float ss = v.x * v.x + v.y * v.y + v.z * v.z + v.w * v.w;
#pragma unroll
  for (int off = 32; off > 0; off >>= 1) ss += __shfl_xor(ss, off);
  float scale = 1.0f / fmaxf(sqrtf(ss), 1e-12f);
  float o0 = v.x * scale, o1 = v.y * scale, o2 = v.z * scale, o3 = v.w * scale;
  ushort4 ob;
  ob.x = f2bf(o0); ob.y = f2bf(o1); ob.z = f2bf(o2); ob.w = f2bf(o3);
  *reinterpret_cast<ushort4*>(ebf + row * DIM + lane * 4) = ob;
  int lab = labels[row];
  float* srow = sums + lab * DIM + lane * 4;
  atomicAdd(srow + 0, o0);
  atomicAdd(srow + 1, o1);
  atomicAdd(srow + 2, o2);
  atomicAdd(srow + 3, o3);
  if (lane == 0) atomicAdd(counts + lab, 1);
}

// ---- 2. protos = normalize(sums / max(count,1)) -> bf16 ----
__global__ __launch_bounds__(256) void k_protos(
    const float* __restrict__ sums, const int* __restrict__ counts,
    unsigned short* __restrict__ pbf) {
  int wid = threadIdx.x >> 6, lane = threadIdx.x & 63;
  int s = blockIdx.x * 4 + wid;
  const float4 sv = *reinterpret_cast<const float4*>(sums + s * DIM + lane * 4);
  float inv = 1.0f / fmaxf((float)counts[s], 1.0f);
  float m0 = sv.x * inv, m1 = sv.y * inv, m2 = sv.z * inv, m3 = sv.w * inv;
  float ss = m0 * m0 + m1 * m1 + m2 * m2 + m3 * m3;
#pragma unroll
  for (int off = 32; off > 0; off >>= 1) ss += __shfl_xor(ss, off);
  float scale = 1.0f / fmaxf(sqrtf(ss), 1e-12f);
  ushort4 ob;
  ob.x = f2bf(m0 * scale); ob.y = f2bf(m1 * scale);
  ob.z = f2bf(m2 * scale); ob.w = f2bf(m3 * scale);
  *reinterpret_cast<ushort4*>(pbf + s * DIM + lane * 4) = ob;
}

// ---- 3. positive_sim[i] = dot(e_bf16[i], protos_bf16[labels[i]]) in fp32 ----
__global__ __launch_bounds__(256) void k_pos(
    const unsigned short* __restrict__ ebf, const unsigned short* __restrict__ pbf,
    const int* __restrict__ labels, float* __restrict__ pos) {
  int wid = threadIdx.x >> 6, lane = threadIdx.x & 63;
  int row = blockIdx.x * 4 + wid;
  int lab = labels[row];
  ushort4 ev = *reinterpret_cast<const ushort4*>(ebf + row * DIM + lane * 4);
  ushort4 pv = *reinterpret_cast<const ushort4*>(pbf + lab * DIM + lane * 4);
  float d = bf2f(ev.x) * bf2f(pv.x) + bf2f(ev.y) * bf2f(pv.y) +
            bf2f(ev.z) * bf2f(pv.z) + bf2f(ev.w) * bf2f(pv.w);
#pragma unroll
  for (int off = 32; off > 0; off >>= 1) d += __shfl_xor(d, off);
  if (lane == 0) pos[row] = d;
}

// ---- 4. fused GEMM + diag-margin + row-max ----
// grid (64, CS): blockIdx.x -> 128-row strip, blockIdx.y -> 2048-col slice.
// Waves 0/1 (wc=0/64) share rows 0..63; waves 2/3 share rows 64..127.
// Each wc-half therefore writes its OWN negp slice: slice = blockIdx.y*2 + (wid&1).
__global__ __launch_bounds__(256) void k_gemm_negmax(
    const unsigned short* __restrict__ E, const unsigned short* __restrict__ P,
    float* __restrict__ negp) {
  extern __shared__ unsigned short sm[];
  unsigned short* As = sm;             // [128][256] bf16
  unsigned short* Bs = sm + 128 * DIM; // [128][256] bf16
  const int tid = threadIdx.x;
  const int lane = tid & 63, wid = tid >> 6;
  const int wr = (wid >> 1) * 64, wc = (wid & 1) * 64;
  const int rowBase = blockIdx.x * 128;
  const int colBase0 = blockIdx.y * 2048;
  const int l16 = lane & 15, lk = lane >> 4;

  // stage A strip (64 KB), resident for whole kernel
  {
    const char* gA = reinterpret_cast<const char*>(E + rowBase * DIM);
    char* lA = reinterpret_cast<char*>(As);
#pragma unroll
    for (int it = 0; it < 16; ++it) {
      int off = it * 4096 + wid * 1024;
      gload_lds16(gA + off + lane * 16, lA + off);
    }
  }

  float rmax[4][4];
#pragma unroll
  for (int m = 0; m < 4; ++m)
#pragma unroll
    for (int r = 0; r < 4; ++r) rmax[m][r] = -3.0e38f;

  for (int ct = 0; ct < 2048 / 128; ++ct) {
    __syncthreads();  // prev-iter B reads done (and A staged on first iter)
    {
      const char* gB =
          reinterpret_cast<const char*>(P + (colBase0 + ct * 128) * DIM);
      char* lB = reinterpret_cast<char*>(Bs);
#pragma unroll
      for (int it = 0; it < 16; ++it) {
        int off = it * 4096 + wid * 1024;
        gload_lds16(gB + off + lane * 16, lB + off);
      }
    }
    __syncthreads();

    f32x4 acc[4][4] = {};
#pragma unroll
    for (int ks = 0; ks < 8; ++ks) {
      short8 a[4], b[4];
#pragma unroll
      for (int m = 0; m < 4; ++m) {
        int row = wr + m * 16 + l16;
        a[m] = *reinterpret_cast<const short8*>(As + row * DIM + ks * 32 + lk * 8);
      }
#pragma unroll
      for (int n = 0; n < 4; ++n) {
        int col = wc + n * 16 + l16;
        b[n] = *reinterpret_cast<const short8*>(Bs + col * DIM + ks * 32 + lk * 8);
      }
#pragma unroll
      for (int m = 0; m < 4; ++m)
#pragma unroll
        for (int n = 0; n < 4; ++n)
          acc[m][n] =
              __builtin_amdgcn_mfma_f32_16x16x32_bf16(a[m], b[n], acc[m][n], 0, 0, 0);
    }

    // epilogue: running max with diagonal margin
#pragma unroll
    for (int m = 0; m < 4; ++m) {
      int growb = rowBase + wr + m * 16 + lk * 4;
#pragma unroll
      for (int n = 0; n < 4; ++n) {
        int gcol = colBase0 + ct * 128 + wc + n * 16 + l16;
#pragma unroll
        for (int r = 0; r < 4; ++r) {
          float v = acc[m][n][r];
          if (growb + r == gcol) v -= MARGIN_F;
          rmax[m][r] = fmaxf(rmax[m][r], v);
        }
      }
    }
  }

  // max across the 16 column-lanes of each row group, then write to the
  // per-(col-slice, wc-half) slice -- NO cross-wave write sharing.
  const int slice = blockIdx.y * 2 + (wid & 1);
#pragma unroll
  for (int m = 0; m < 4; ++m) {
#pragma unroll
    for (int r = 0; r < 4; ++r) {
      float v = rmax[m][r];
      v = fmaxf(v, __shfl_xor(v, 1));
      v = fmaxf(v, __shfl_xor(v, 2));
      v = fmaxf(v, __shfl_xor(v, 4));
      v = fmaxf(v, __shfl_xor(v, 8));
      if (l16 == 0) {
        int grow = rowBase + wr + m * 16 + lk * 4 + r;
        negp[slice * B_ROWS + grow] = v;
      }
    }
  }
}

// ---- 5. final: neg = max over 2*CS partials, loss = mean(relu(neg-pos+m)) ----
__global__ __launch_bounds__(256) void k_loss(
    const float* __restrict__ negp, const float* __restrict__ pos,
    float* __restrict__ out) {
  int tid = threadIdx.x;
  float s = 0.f;
  for (int i = tid; i < B_ROWS; i += 256) {
    float n = negp[i];
#pragma unroll
    for (int s8 = 1; s8 < 2 * CS; ++s8) n = fmaxf(n, negp[s8 * B_ROWS + i]);
    float t = n - pos[i] + MARGIN_F;
    s += fmaxf(t, 0.f);
  }
#pragma unroll
  for (int off = 32; off > 0; off >>= 1) s += __shfl_xor(s, off);
  __shared__ float red[4];
  if ((tid & 63) == 0) red[tid >> 6] = s;
  __syncthreads();
  if (tid == 0) out[0] = (red[0] + red[1] + red[2] + red[3]) * (1.0f / B_ROWS);
}

extern "C" void kernel_launch(void* const* d_in, const int* in_sizes, int n_in,
                              void* d_out, int out_size, void* d_ws, size_t ws_size,
                              hipStream_t stream) {
  const float* emb = (const float*)d_in[0];
  const int* labels = (const int*)d_in[1];
  float* out = (float*)d_out;

  char* ws = (char*)d_ws;
  float* sums = (float*)ws;                                   // 8 MB
  int* counts = (int*)(ws + 8 * 1024 * 1024);                 // 32 KB
  unsigned short* ebf =
      (unsigned short*)(ws + 8 * 1024 * 1024 + 32 * 1024);    // 4 MB
  unsigned short* pbf =
      (unsigned short*)(ws + 12 * 1024 * 1024 + 32 * 1024);   // 4 MB
  float* pos = (float*)(ws + 16 * 1024 * 1024 + 32 * 1024);   // 32 KB
  float* negp = (float*)(ws + 16 * 1024 * 1024 + 64 * 1024);  // 2*CS*32 KB

  hipMemsetAsync(sums, 0, 8 * 1024 * 1024 + 32 * 1024, stream);
  k_norm_scatter<<<B_ROWS / 4, 256, 0, stream>>>(emb, labels, ebf, sums, counts);
  k_protos<<<B_ROWS / 4, 256, 0, stream>>>(sums, counts, pbf);
  k_pos<<<B_ROWS / 4, 256, 0, stream>>>(ebf, pbf, labels, pos);
  hipFuncSetAttribute((const void*)k_gemm_negmax,
                      hipFuncAttributeMaxDynamicSharedMemorySize, 131072);
  k_gemm_negmax<<<dim3(64, CS), 256, 131072, stream>>>(ebf, pbf, negp);
  k_loss<<<1, 256, 0, stream>>>(negp, pos, out);
}

// Round 3
// 143.168 us; speedup vs baseline: 1.3215x; 1.3215x over previous
//
#include <hip/hip_runtime.h>
#include <hip/hip_bf16.h>

typedef __attribute__((ext_vector_type(8))) short short8;
typedef __attribute__((ext_vector_type(4))) float f32x4;

#define B_ROWS 8192
#define DIM 256
#define CS 8                  // column slices -> grid.y
#define NSLICE (CS * 2)       // negp slices (per col-slice x wc-half)
#define MARGIN_F 0.2f
#define BUCKET_CAP 32

__device__ __forceinline__ unsigned short f2bf(float x) {
  unsigned int u = __float_as_uint(x);
  unsigned int r = (u + 0x7fffu + ((u >> 16) & 1u)) >> 16;
  return (unsigned short)r;
}
__device__ __forceinline__ float bf2f(unsigned short h) {
  return __uint_as_float(((unsigned int)h) << 16);
}

__device__ __forceinline__ void gload_lds16(const void* g, void* l) {
  __builtin_amdgcn_global_load_lds(
      (const __attribute__((address_space(1))) unsigned int*)g,
      (__attribute__((address_space(3))) unsigned int*)l, 16, 0, 0);
}

// ---- 1. normalize rows -> bf16 e; build label->rows bucket index ----
__global__ __launch_bounds__(256) void k_norm_index(
    const float* __restrict__ emb, const int* __restrict__ labels,
    unsigned short* __restrict__ ebf, int* __restrict__ cursor,
    int* __restrict__ bucket) {
  int wid = threadIdx.x >> 6, lane = threadIdx.x & 63;
  int row = blockIdx.x * 4 + wid;
  const float4 v = *reinterpret_cast<const float4*>(emb + row * DIM + lane * 4);
  float ss = v.x * v.x + v.y * v.y + v.z * v.z + v.w * v.w;
#pragma unroll
  for (int off = 32; off > 0; off >>= 1) ss += __shfl_xor(ss, off);
  float scale = 1.0f / fmaxf(sqrtf(ss), 1e-12f);
  ushort4 ob;
  ob.x = f2bf(v.x * scale); ob.y = f2bf(v.y * scale);
  ob.z = f2bf(v.z * scale); ob.w = f2bf(v.w * scale);
  *reinterpret_cast<ushort4*>(ebf + row * DIM + lane * 4) = ob;
  if (lane == 0) {
    int lab = labels[row];
    int slot = atomicAdd(cursor + lab, 1);
    if (slot < BUCKET_CAP) bucket[lab * BUCKET_CAP + slot] = row;
  }
}

// ---- 2. protos: gather-sum member rows (normalize makes /count a no-op) ----
__global__ __launch_bounds__(256) void k_protos_gather(
    const unsigned short* __restrict__ ebf, const int* __restrict__ cursor,
    const int* __restrict__ bucket, unsigned short* __restrict__ pbf) {
  int wid = threadIdx.x >> 6, lane = threadIdx.x & 63;
  int s = blockIdx.x * 4 + wid;
  int c = cursor[s];
  if (c > BUCKET_CAP) c = BUCKET_CAP;
  float a0 = 0.f, a1 = 0.f, a2 = 0.f, a3 = 0.f;
  for (int k = 0; k < c; ++k) {
    int row = bucket[s * BUCKET_CAP + k];
    ushort4 ev = *reinterpret_cast<const ushort4*>(ebf + row * DIM + lane * 4);
    a0 += bf2f(ev.x); a1 += bf2f(ev.y); a2 += bf2f(ev.z); a3 += bf2f(ev.w);
  }
  float ss = a0 * a0 + a1 * a1 + a2 * a2 + a3 * a3;
#pragma unroll
  for (int off = 32; off > 0; off >>= 1) ss += __shfl_xor(ss, off);
  float scale = 1.0f / fmaxf(sqrtf(ss), 1e-12f);
  ushort4 ob;
  ob.x = f2bf(a0 * scale); ob.y = f2bf(a1 * scale);
  ob.z = f2bf(a2 * scale); ob.w = f2bf(a3 * scale);
  *reinterpret_cast<ushort4*>(pbf + s * DIM + lane * 4) = ob;
}

// ---- 3. positive_sim[i] = dot(e_bf16[i], protos_bf16[labels[i]]) ----
__global__ __launch_bounds__(256) void k_pos(
    const unsigned short* __restrict__ ebf, const unsigned short* __restrict__ pbf,
    const int* __restrict__ labels, float* __restrict__ pos) {
  int wid = threadIdx.x >> 6, lane = threadIdx.x & 63;
  int row = blockIdx.x * 4 + wid;
  int lab = labels[row];
  ushort4 ev = *reinterpret_cast<const ushort4*>(ebf + row * DIM + lane * 4);
  ushort4 pv = *reinterpret_cast<const ushort4*>(pbf + lab * DIM + lane * 4);
  float d = bf2f(ev.x) * bf2f(pv.x) + bf2f(ev.y) * bf2f(pv.y) +
            bf2f(ev.z) * bf2f(pv.z) + bf2f(ev.w) * bf2f(pv.w);
#pragma unroll
  for (int off = 32; off > 0; off >>= 1) d += __shfl_xor(d, off);
  if (lane == 0) pos[row] = d;
}

// ---- 4. fused GEMM + diag-margin + row-max ----
// A fragments live in registers (K=256 resident, 128 VGPR/wave).
// B staged in FRAGMENT ORDER: LDS chunk c=(hb*4+n)*8+ks holds, at
// c*1024 + lane*16 bytes, P[colTile + hb*64 + n*16 + (lane&15)]
// [ks*32 + (lane>>4)*8 ..+8]. ds_read_b128 is then a contiguous 1024B
// wave read -> zero bank conflicts. gload_lds dest stays linear
// (wave-uniform base + lane*16); the permutation lives in the GLOBAL
// source address (rule #21-clean).
__global__ __launch_bounds__(256, 2) void k_gemm_negmax(
    const unsigned short* __restrict__ E, const unsigned short* __restrict__ P,
    float* __restrict__ negp) {
  extern __shared__ unsigned short sm[];  // 64 KB B fragments
  const int tid = threadIdx.x;
  const int lane = tid & 63, wid = tid >> 6;
  const int l16 = lane & 15, lk = lane >> 4;
  const int wr = (wid >> 1) * 64;  // row half offset
  const int wch = wid & 1;         // col half index
  const int rowBase = blockIdx.x * 128;
  const int colBase0 = blockIdx.y * (128 * (8192 / CS / 128));  // *1024

  auto stageB = [&](int colTile) {
#pragma unroll
    for (int it = 0; it < 16; ++it) {
      int c = it * 4 + wid;
      int prow = colTile + ((c >> 5) << 6) + (((c >> 3) & 3) << 4) + l16;
      int pel = ((c & 7) << 5) + (lk << 3);
      gload_lds16(P + prow * DIM + pel, sm + c * 512 + lane * 8);
    }
  };

  stageB(colBase0);

  // A fragments -> registers (compile-time indices only)
  short8 areg[4][8];
#pragma unroll
  for (int m = 0; m < 4; ++m)
#pragma unroll
    for (int ks = 0; ks < 8; ++ks)
      areg[m][ks] = *reinterpret_cast<const short8*>(
          E + (rowBase + wr + m * 16 + l16) * DIM + ks * 32 + lk * 8);

  float rmax[4][4];
#pragma unroll
  for (int m = 0; m < 4; ++m)
#pragma unroll
    for (int r = 0; r < 4; ++r) rmax[m][r] = -3.0e38f;

  for (int ct = 0; ct < 8192 / CS / 128; ++ct) {
    __syncthreads();  // drains vmcnt -> Bs(ct) (and areg on ct==0) ready

    f32x4 acc[4][4] = {};
#pragma unroll
    for (int ks = 0; ks < 8; ++ks) {
      short8 b[4];
#pragma unroll
      for (int n = 0; n < 4; ++n)
        b[n] = *reinterpret_cast<const short8*>(
            sm + ((wch * 4 + n) * 8 + ks) * 512 + lane * 8);
#pragma unroll
      for (int m = 0; m < 4; ++m)
#pragma unroll
        for (int n = 0; n < 4; ++n)
          acc[m][n] = __builtin_amdgcn_mfma_f32_16x16x32_bf16(
              areg[m][ks], b[n], acc[m][n], 0, 0, 0);
    }

    __syncthreads();  // all waves done reading Bs(ct)
    if (ct + 1 < 8192 / CS / 128) stageB(colBase0 + (ct + 1) * 128);

    // epilogue (VALU only) overlaps the staging flight
    const int colT = colBase0 + ct * 128 + wch * 64;
#pragma unroll
    for (int m = 0; m < 4; ++m) {
      int growb = rowBase + wr + m * 16 + lk * 4;
#pragma unroll
      for (int n = 0; n < 4; ++n) {
        int gcol = colT + n * 16 + l16;
#pragma unroll
        for (int r = 0; r < 4; ++r) {
          float v = acc[m][n][r];
          if (growb + r == gcol) v -= MARGIN_F;
          rmax[m][r] = fmaxf(rmax[m][r], v);
        }
      }
    }
  }

  const int slice = blockIdx.y * 2 + wch;
#pragma unroll
  for (int m = 0; m < 4; ++m) {
#pragma unroll
    for (int r = 0; r < 4; ++r) {
      float v = rmax[m][r];
      v = fmaxf(v, __shfl_xor(v, 1));
      v = fmaxf(v, __shfl_xor(v, 2));
      v = fmaxf(v, __shfl_xor(v, 4));
      v = fmaxf(v, __shfl_xor(v, 8));
      if (l16 == 0) {
        int grow = rowBase + wr + m * 16 + lk * 4 + r;
        negp[slice * B_ROWS + grow] = v;
      }
    }
  }
}

// ---- 5. loss: neg = max over slices, mean(relu(neg-pos+m)) -> atomicAdd ----
__global__ __launch_bounds__(256) void k_loss_part(
    const float* __restrict__ negp, const float* __restrict__ pos,
    float* __restrict__ out) {
  int i = blockIdx.x * 256 + threadIdx.x;
  float n = negp[i];
#pragma unroll
  for (int s = 1; s < NSLICE; ++s) n = fmaxf(n, negp[s * B_ROWS + i]);
  float t = fmaxf(n - pos[i] + MARGIN_F, 0.f);
#pragma unroll
  for (int off = 32; off > 0; off >>= 1) t += __shfl_xor(t, off);
  __shared__ float red[4];
  if ((threadIdx.x & 63) == 0) red[threadIdx.x >> 6] = t;
  __syncthreads();
  if (threadIdx.x == 0)
    atomicAdd(out, (red[0] + red[1] + red[2] + red[3]) * (1.0f / B_ROWS));
}

extern "C" void kernel_launch(void* const* d_in, const int* in_sizes, int n_in,
                              void* d_out, int out_size, void* d_ws, size_t ws_size,
                              hipStream_t stream) {
  const float* emb = (const float*)d_in[0];
  const int* labels = (const int*)d_in[1];

  char* ws = (char*)d_ws;
  int* cursor = (int*)ws;                                        // 32 KB
  int* bucket = (int*)(ws + 32 * 1024);                          // 1 MB
  unsigned short* ebf =
      (unsigned short*)(ws + 32 * 1024 + 1024 * 1024);           // 4 MB
  unsigned short* pbf =
      (unsigned short*)(ws + 32 * 1024 + 5 * 1024 * 1024);       // 4 MB
  float* pos = (float*)(ws + 32 * 1024 + 9 * 1024 * 1024);       // 32 KB
  float* negp = (float*)(ws + 64 * 1024 + 9 * 1024 * 1024);      // 512 KB

  hipMemsetAsync(cursor, 0, 32 * 1024, stream);
  hipMemsetAsync(d_out, 0, sizeof(float), stream);
  k_norm_index<<<B_ROWS / 4, 256, 0, stream>>>(emb, labels, ebf, cursor, bucket);
  k_protos_gather<<<B_ROWS / 4, 256, 0, stream>>>(ebf, cursor, bucket, pbf);
  k_pos<<<B_ROWS / 4, 256, 0, stream>>>(ebf, pbf, labels, pos);
  hipFuncSetAttribute((const void*)k_gemm_negmax,
                      hipFuncAttributeMaxDynamicSharedMemorySize, 65536);
  k_gemm_negmax<<<dim3(64, CS), 256, 65536, stream>>>(ebf, pbf, negp);
  k_loss_part<<<32, 256, 0, stream>>>(negp, pos, (float*)d_out);
}

// Round 5
// 116.767 us; speedup vs baseline: 1.6202x; 1.2261x over previous
//
#include <hip/hip_runtime.h>
#include <hip/hip_bf16.h>

typedef __attribute__((ext_vector_type(8))) short short8;
typedef __attribute__((ext_vector_type(4))) float f32x4;

#define B_ROWS 8192
#define DIM 256
#define CS 8                  // column slices -> grid.y (1024 cols each)
#define NT 16                 // 64-col tiles per slice
#define NSLICE (CS * 2)       // negp slices (col-slice x wch-half)
#define MARGIN_F 0.2f
#define BUCKET_CAP 32

__device__ __forceinline__ unsigned short f2bf(float x) {
  unsigned int u = __float_as_uint(x);
  unsigned int r = (u + 0x7fffu + ((u >> 16) & 1u)) >> 16;
  return (unsigned short)r;
}
__device__ __forceinline__ float bf2f(unsigned short h) {
  return __uint_as_float(((unsigned int)h) << 16);
}

__device__ __forceinline__ void gload_lds16(const void* g, void* l) {
  __builtin_amdgcn_global_load_lds(
      (const __attribute__((address_space(1))) unsigned int*)g,
      (__attribute__((address_space(3))) unsigned int*)l, 16, 0, 0);
}

// ---- 1. normalize rows -> bf16 e; build label->rows bucket index ----
__global__ __launch_bounds__(256) void k_norm_index(
    const float* __restrict__ emb, const int* __restrict__ labels,
    unsigned short* __restrict__ ebf, int* __restrict__ cursor,
    int* __restrict__ bucket) {
  int wid = threadIdx.x >> 6, lane = threadIdx.x & 63;
  int row = blockIdx.x * 4 + wid;
  const float4 v = *reinterpret_cast<const float4*>(emb + row * DIM + lane * 4);
  float ss = v.x * v.x + v.y * v.y + v.z * v.z + v.w * v.w;
#pragma unroll
  for (int off = 32; off > 0; off >>= 1) ss += __shfl_xor(ss, off);
  float scale = 1.0f / fmaxf(sqrtf(ss), 1e-12f);
  ushort4 ob;
  ob.x = f2bf(v.x * scale); ob.y = f2bf(v.y * scale);
  ob.z = f2bf(v.z * scale); ob.w = f2bf(v.w * scale);
  *reinterpret_cast<ushort4*>(ebf + row * DIM + lane * 4) = ob;
  if (lane == 0) {
    int lab = labels[row];
    int slot = atomicAdd(cursor + lab, 1);
    if (slot < BUCKET_CAP) bucket[lab * BUCKET_CAP + slot] = row;
  }
}

// ---- 2. protos: gather-sum member rows (normalize makes /count a no-op) ----
__global__ __launch_bounds__(256) void k_protos_gather(
    const unsigned short* __restrict__ ebf, const int* __restrict__ cursor,
    const int* __restrict__ bucket, unsigned short* __restrict__ pbf) {
  int wid = threadIdx.x >> 6, lane = threadIdx.x & 63;
  int s = blockIdx.x * 4 + wid;
  int c = cursor[s];
  if (c > BUCKET_CAP) c = BUCKET_CAP;
  float a0 = 0.f, a1 = 0.f, a2 = 0.f, a3 = 0.f;
  for (int k = 0; k < c; ++k) {
    int row = bucket[s * BUCKET_CAP + k];
    ushort4 ev = *reinterpret_cast<const ushort4*>(ebf + row * DIM + lane * 4);
    a0 += bf2f(ev.x); a1 += bf2f(ev.y); a2 += bf2f(ev.z); a3 += bf2f(ev.w);
  }
  float ss = a0 * a0 + a1 * a1 + a2 * a2 + a3 * a3;
#pragma unroll
  for (int off = 32; off > 0; off >>= 1) ss += __shfl_xor(ss, off);
  float scale = 1.0f / fmaxf(sqrtf(ss), 1e-12f);
  ushort4 ob;
  ob.x = f2bf(a0 * scale); ob.y = f2bf(a1 * scale);
  ob.z = f2bf(a2 * scale); ob.w = f2bf(a3 * scale);
  *reinterpret_cast<ushort4*>(pbf + s * DIM + lane * 4) = ob;
}

// ---- 3. positive_sim[i] = dot(e_bf16[i], protos_bf16[labels[i]]) ----
__global__ __launch_bounds__(256) void k_pos(
    const unsigned short* __restrict__ ebf, const unsigned short* __restrict__ pbf,
    const int* __restrict__ labels, float* __restrict__ pos) {
  int wid = threadIdx.x >> 6, lane = threadIdx.x & 63;
  int row = blockIdx.x * 4 + wid;
  int lab = labels[row];
  ushort4 ev = *reinterpret_cast<const ushort4*>(ebf + row * DIM + lane * 4);
  ushort4 pv = *reinterpret_cast<const ushort4*>(pbf + lab * DIM + lane * 4);
  float d = bf2f(ev.x) * bf2f(pv.x) + bf2f(ev.y) * bf2f(pv.y) +
            bf2f(ev.z) * bf2f(pv.z) + bf2f(ev.w) * bf2f(pv.w);
#pragma unroll
  for (int off = 32; off > 0; off >>= 1) d += __shfl_xor(d, off);
  if (lane == 0) pos[row] = d;
}

// ---- 4. fused GEMM + diag-margin + row-max, DOUBLE-BUFFERED (T3 2-phase) ----
// Geometry: block = 128 rows x 1024-col slice; 4 waves, each owns 64 rows x
// the wch*32 column half of each 64-col tile. A (K=256) resident in regs
// (areg[4][8] = 128 VGPR). B tiles 64 cols x 256 K = 32 KB, staged in
// FRAGMENT ORDER (zero bank conflicts, round-3-verified), double-buffered:
// stage(t+1)->buf^1 issued BEFORE compute(t)<-buf, one barrier per iter.
// Writes and reads never touch the same buffer within a barrier interval,
// so scheduler motion of global_load_lds around barriers is harmless
// (round-4 failure mode eliminated by construction).
// waves_per_eu(2,2) pins the allocator's occupancy target: VGPR cap 256
// (demand ~210); (256,2) launch_bounds empirically capped at 128 + spills.
__global__ __attribute__((amdgpu_flat_work_group_size(256, 256)))
__attribute__((amdgpu_waves_per_eu(2, 2))) void k_gemm_negmax(
    const unsigned short* __restrict__ E, const unsigned short* __restrict__ P,
    float* __restrict__ negp) {
  __shared__ unsigned short smbuf[2][32 * 512];  // 2 x 32 KB
  const int tid = threadIdx.x;
  const int lane = tid & 63, wid = tid >> 6;
  const int l16 = lane & 15, lk = lane >> 4;
  const int wr = (wid >> 1) * 64;  // row half
  const int wch = wid & 1;         // 32-col half of each tile
  const int rowBase = blockIdx.x * 128;
  const int colBase0 = blockIdx.y * 1024;

  // chunk c in [0,32): c = (half*2 + n)*8 + ks. At bytes c*1024 + lane*16:
  // P[colTile + (c>>4)*32 + ((c>>3)&1)*16 + l16][(c&7)*32 + lk*8 ..+8]
  auto stageB = [&](int buf, int colTile) {
#pragma unroll
    for (int it = 0; it < 8; ++it) {
      int c = it * 4 + wid;
      int prow = colTile + ((c >> 4) << 5) + (((c >> 3) & 1) << 4) + l16;
      int pel = ((c & 7) << 5) + (lk << 3);
      gload_lds16(P + prow * DIM + pel, &smbuf[buf][c * 512 + lane * 8]);
    }
  };

  stageB(0, colBase0);

  // A fragments -> registers (compile-time indices only)
  short8 areg[4][8];
#pragma unroll
  for (int m = 0; m < 4; ++m)
#pragma unroll
    for (int ks = 0; ks < 8; ++ks)
      areg[m][ks] = *reinterpret_cast<const short8*>(
          E + (rowBase + wr + m * 16 + l16) * DIM + ks * 32 + lk * 8);

  float rmax[4][4];
#pragma unroll
  for (int m = 0; m < 4; ++m)
#pragma unroll
    for (int r = 0; r < 4; ++r) rmax[m][r] = -3.0e38f;

  __syncthreads();  // buf0 staged + areg loaded (vmcnt drained by barrier)

  for (int ct = 0; ct < NT; ++ct) {
    if (ct + 1 < NT) stageB((ct + 1) & 1, colBase0 + (ct + 1) * 64);

    const unsigned short* bs = smbuf[ct & 1];
    f32x4 acc[4][2] = {};
#pragma unroll
    for (int ks = 0; ks < 8; ++ks) {
      short8 b[2];
#pragma unroll
      for (int n = 0; n < 2; ++n)
        b[n] = *reinterpret_cast<const short8*>(
            bs + ((wch * 2 + n) * 8 + ks) * 512 + lane * 8);
#pragma unroll
      for (int m = 0; m < 4; ++m)
#pragma unroll
        for (int n = 0; n < 2; ++n)
          acc[m][n] = __builtin_amdgcn_mfma_f32_16x16x32_bf16(
              areg[m][ks], b[n], acc[m][n], 0, 0, 0);
    }

    // epilogue (VALU on regs) overlaps the staging flight
    const int colT = colBase0 + ct * 64 + wch * 32;
#pragma unroll
    for (int m = 0; m < 4; ++m) {
      int growb = rowBase + wr + m * 16 + lk * 4;
#pragma unroll
      for (int n = 0; n < 2; ++n) {
        int gcol = colT + n * 16 + l16;
#pragma unroll
        for (int r = 0; r < 4; ++r) {
          float v = acc[m][n][r];
          if (growb + r == gcol) v -= MARGIN_F;
          rmax[m][r] = fmaxf(rmax[m][r], v);
        }
      }
    }

    __syncthreads();  // drains stage vmcnt + ds_reads; flip buffers
  }

  const int slice = blockIdx.y * 2 + wch;
#pragma unroll
  for (int m = 0; m < 4; ++m) {
#pragma unroll
    for (int r = 0; r < 4; ++r) {
      float v = rmax[m][r];
      v = fmaxf(v, __shfl_xor(v, 1));
      v = fmaxf(v, __shfl_xor(v, 2));
      v = fmaxf(v, __shfl_xor(v, 4));
      v = fmaxf(v, __shfl_xor(v, 8));
      if (l16 == 0) {
        int grow = rowBase + wr + m * 16 + lk * 4 + r;
        negp[slice * B_ROWS + grow] = v;
      }
    }
  }
}

// ---- 5. loss: neg = max over slices, mean(relu(neg-pos+m)) -> atomicAdd ----
__global__ __launch_bounds__(256) void k_loss_part(
    const float* __restrict__ negp, const float* __restrict__ pos,
    float* __restrict__ out) {
  int i = blockIdx.x * 256 + threadIdx.x;
  float n = negp[i];
#pragma unroll
  for (int s = 1; s < NSLICE; ++s) n = fmaxf(n, negp[s * B_ROWS + i]);
  float t = fmaxf(n - pos[i] + MARGIN_F, 0.f);
#pragma unroll
  for (int off = 32; off > 0; off >>= 1) t += __shfl_xor(t, off);
  __shared__ float red[4];
  if ((threadIdx.x & 63) == 0) red[threadIdx.x >> 6] = t;
  __syncthreads();
  if (threadIdx.x == 0)
    atomicAdd(out, (red[0] + red[1] + red[2] + red[3]) * (1.0f / B_ROWS));
}

extern "C" void kernel_launch(void* const* d_in, const int* in_sizes, int n_in,
                              void* d_out, int out_size, void* d_ws, size_t ws_size,
                              hipStream_t stream) {
  const float* emb = (const float*)d_in[0];
  const int* labels = (const int*)d_in[1];

  char* ws = (char*)d_ws;
  int* cursor = (int*)ws;                                        // 32 KB
  int* bucket = (int*)(ws + 32 * 1024);                          // 1 MB
  unsigned short* ebf =
      (unsigned short*)(ws + 32 * 1024 + 1024 * 1024);           // 4 MB
  unsigned short* pbf =
      (unsigned short*)(ws + 32 * 1024 + 5 * 1024 * 1024);       // 4 MB
  float* pos = (float*)(ws + 32 * 1024 + 9 * 1024 * 1024);       // 32 KB
  float* negp = (float*)(ws + 64 * 1024 + 9 * 1024 * 1024);      // 512 KB

  hipMemsetAsync(cursor, 0, 32 * 1024, stream);
  hipMemsetAsync(d_out, 0, sizeof(float), stream);
  k_norm_index<<<B_ROWS / 4, 256, 0, stream>>>(emb, labels, ebf, cursor, bucket);
  k_protos_gather<<<B_ROWS / 4, 256, 0, stream>>>(ebf, cursor, bucket, pbf);
  k_pos<<<B_ROWS / 4, 256, 0, stream>>>(ebf, pbf, labels, pos);
  k_gemm_negmax<<<dim3(64, CS), 256, 0, stream>>>(ebf, pbf, negp);
  k_loss_part<<<32, 256, 0, stream>>>(negp, pos, (float*)d_out);
}